// Round 8
// baseline (5929.375 us; speedup 1.0000x reference)
//
#include <hip/hip_runtime.h>
#include <hip/hip_fp16.h>
#include <math.h>

#define Nn 50000
#define Ff 16
#define Tt 12
#define Hh 64
#define Ee 1600000
#define Cc 80  // F + H

static __device__ __forceinline__ float sigmoidf_(float x) { return 1.0f / (1.0f + expf(-x)); }

// ---------------- CSR build ----------------
// dc[d] accumulates (count << 42) + round(ew * 2^21) in one u64 atomic.
__global__ void k_deg(const int* __restrict__ ei, const float* __restrict__ ew,
                      unsigned long long* __restrict__ dc) {
  int e = blockIdx.x * blockDim.x + threadIdx.x;
  if (e >= Ee) return;
  int d = ei[Ee + e];
  unsigned long long pk = (1ULL << 42) + (unsigned long long)(ew[e] * 2097152.0f + 0.5f);
  atomicAdd(&dc[d], pk);
}

__global__ void k_dis(const unsigned long long* __restrict__ dc,
                      float* __restrict__ dis, int* __restrict__ cnt) {
  int i = blockIdx.x * blockDim.x + threadIdx.x;
  if (i >= Nn) return;
  unsigned long long v = dc[i];
  cnt[i] = (int)(v >> 42);
  float deg = (float)(v & ((1ULL << 42) - 1)) * (1.0f / 2097152.0f);
  dis[i] = 1.0f / sqrtf(deg + 1.0f);
}

__global__ __launch_bounds__(1024) void k_scan(const int* __restrict__ cnt,
                                               int* __restrict__ rp, int* __restrict__ cur) {
  __shared__ int ss[1024];
  const int ITEMS = (Nn + 1023) / 1024;  // 49
  int t = threadIdx.x;
  int base = t * ITEMS;
  int sum = 0;
  for (int k = 0; k < ITEMS; k++) {
    int idx = base + k;
    if (idx < Nn) sum += cnt[idx];
  }
  ss[t] = sum;
  __syncthreads();
  for (int off = 1; off < 1024; off <<= 1) {
    int v = (t >= off) ? ss[t - off] : 0;
    __syncthreads();
    ss[t] += v;
    __syncthreads();
  }
  int run = ss[t] - sum;  // exclusive prefix
  for (int k = 0; k < ITEMS; k++) {
    int idx = base + k;
    if (idx < Nn) { rp[idx] = run; cur[idx] = run; run += cnt[idx]; }
  }
  if (t == 0) rp[Nn] = Ee;
}

// edge2[pos] = {src, normalized weight}: one scattered 8-B store per edge
__global__ void k_scatter(const int* __restrict__ ei, const float* __restrict__ ew,
                          const float* __restrict__ dis, int* __restrict__ cur,
                          int2* __restrict__ edge2) {
  int e = blockIdx.x * blockDim.x + threadIdx.x;
  if (e >= Ee) return;
  int s = ei[e];
  int d = ei[Ee + e];
  float w = ew[e] * dis[s] * dis[d];
  int pos = atomicAdd(&cur[d], 1);
  edge2[pos] = make_int2(s, __float_as_int(w));
}

// ---------------- x fp32 -> fp16 (once) ----------------
__global__ void k_cvt_x(const float* __restrict__ x, __half* __restrict__ x16) {
  size_t idx = (size_t)blockIdx.x * blockDim.x + threadIdx.x;
  const size_t total = (size_t)Nn * Ff * Tt;
  if (idx < total) x16[idx] = __float2half(x[idx]);
}

// ---------------- Px16[t][i][f] = (A_hat @ x): wave per node, 48 lanes x 8B per edge ----------------
__global__ __launch_bounds__(256) void k_agg_px(
    const float* __restrict__ x, const __half* __restrict__ x16, __half* __restrict__ Px16,
    const int* __restrict__ rp, const int2* __restrict__ edge2,
    const float* __restrict__ dis) {
  int i = blockIdx.x * 4 + (threadIdx.x >> 6);
  if (i >= Nn) return;
  int lane = threadIdx.x & 63;
  const int R = Ff * Tt;  // 192
  const bool act = lane < 48;
  float d = dis[i], sn = d * d;
  float a0 = 0.f, a1 = 0.f, a2 = 0.f, a3 = 0.f;
  if (act) {
    float4 sv = *(const float4*)(x + (size_t)i * R + 4 * lane);  // self, fp32 exact
    a0 = sn * sv.x; a1 = sn * sv.y; a2 = sn * sv.z; a3 = sn * sv.w;
  }
  int jb = rp[i], je = rp[i + 1];
  for (int j = jb; j < je; j += 2) {
    int jc1 = min(j + 1, Ee - 1);
    int2 e0 = edge2[j];
    int2 e1 = edge2[jc1];
    float w0 = __int_as_float(e0.y);
    float w1 = (j + 1 < je) ? __int_as_float(e1.y) : 0.f;
    if (act) {
      uint2 g0 = *(const uint2*)(x16 + (size_t)e0.x * R + 4 * lane);
      uint2 g1 = *(const uint2*)(x16 + (size_t)e1.x * R + 4 * lane);
      float2 p01 = __half22float2(*reinterpret_cast<const __half2*>(&g0.x));
      float2 p23 = __half22float2(*reinterpret_cast<const __half2*>(&g0.y));
      float2 q01 = __half22float2(*reinterpret_cast<const __half2*>(&g1.x));
      float2 q23 = __half22float2(*reinterpret_cast<const __half2*>(&g1.y));
      a0 = fmaf(w0, p01.x, a0); a1 = fmaf(w0, p01.y, a1);
      a2 = fmaf(w0, p23.x, a2); a3 = fmaf(w0, p23.y, a3);
      a0 = fmaf(w1, q01.x, a0); a1 = fmaf(w1, q01.y, a1);
      a2 = fmaf(w1, q23.x, a2); a3 = fmaf(w1, q23.y, a3);
    }
  }
  if (act) {
#pragma unroll
    for (int k = 0; k < 4; k++) {
      int cch = 4 * lane + k;           // channel = f*T + t
      int f = cch / Tt, tt = cch % Tt;
      float val = (k == 0) ? a0 : (k == 1) ? a1 : (k == 2) ? a2 : a3;
      Px16[(size_t)tt * Nn * Ff + (size_t)i * Ff + f] = __float2half(val);
    }
  }
}

// ---- shared gather core: one wave aggregates 64 fp16 channels of node i ----
// lanes: g=lane>>4 edge slot, c4=lane&15 channel quad. Result in a0..a3 on lanes 0-15 after reduce.
static __device__ __forceinline__ void gather64(
    const __half* __restrict__ v, int i, int g, int c4,
    const int* __restrict__ rp, const int2* __restrict__ edge2, float sn,
    float& a0, float& a1, float& a2, float& a3) {
  {
    const uint2 gv = *(const uint2*)(v + (size_t)i * Hh + 4 * c4);  // self
    float2 f01 = __half22float2(*reinterpret_cast<const __half2*>(&gv.x));
    float2 f23 = __half22float2(*reinterpret_cast<const __half2*>(&gv.y));
    float ws = (g == 0) ? sn : 0.f;
    a0 = ws * f01.x; a1 = ws * f01.y; a2 = ws * f23.x; a3 = ws * f23.y;
  }
  int jb = rp[i], je = rp[i + 1];
  for (int j0 = jb; j0 < je; j0 += 8) {
    int j1 = j0 + g;
    int j2 = j0 + 4 + g;
    int2 e1 = edge2[min(j1, Ee - 1)];
    int2 e2 = edge2[min(j2, Ee - 1)];
    float w1 = (j1 < je) ? __int_as_float(e1.y) : 0.f;
    float w2 = (j2 < je) ? __int_as_float(e2.y) : 0.f;
    const uint2 g1 = *(const uint2*)(v + (size_t)e1.x * Hh + 4 * c4);
    const uint2 g2 = *(const uint2*)(v + (size_t)e2.x * Hh + 4 * c4);
    float2 p01 = __half22float2(*reinterpret_cast<const __half2*>(&g1.x));
    float2 p23 = __half22float2(*reinterpret_cast<const __half2*>(&g1.y));
    float2 q01 = __half22float2(*reinterpret_cast<const __half2*>(&g2.x));
    float2 q23 = __half22float2(*reinterpret_cast<const __half2*>(&g2.y));
    a0 = fmaf(w1, p01.x, a0); a1 = fmaf(w1, p01.y, a1);
    a2 = fmaf(w1, p23.x, a2); a3 = fmaf(w1, p23.y, a3);
    a0 = fmaf(w2, q01.x, a0); a1 = fmaf(w2, q01.y, a1);
    a2 = fmaf(w2, q23.x, a2); a3 = fmaf(w2, q23.y, a3);
  }
  a0 += __shfl_xor(a0, 16, 64); a1 += __shfl_xor(a1, 16, 64);
  a2 += __shfl_xor(a2, 16, 64); a3 += __shfl_xor(a3, 16, 64);
  a0 += __shfl_xor(a0, 32, 64); a1 += __shfl_xor(a1, 32, 64);
  a2 += __shfl_xor(a2, 32, 64); a3 += __shfl_xor(a3, 32, 64);
}

// ---------------- fused: gather(h16) + z/r GEMM ----------------
// NOTE: no waves-per-EU hint — the 2nd __launch_bounds__ arg forces a VGPR cap
// the compiler satisfies by spilling to scratch (GB-scale WRITE_SIZE, 10-30x dur).
// Measured rounds 2/6. Weights packed (z,r) as __half2: 25KB LDS -> 6 blocks/CU.
__global__ __launch_bounds__(256) void k_zr_f(
    const __half* __restrict__ Px16, const __half* __restrict__ h16,
    const int* __restrict__ rp, const int2* __restrict__ edge2,
    const float* __restrict__ dis,
    const float* __restrict__ Wz, const float* __restrict__ bz,
    const float* __restrict__ Wr, const float* __restrict__ br,
    __half* __restrict__ zb16, __half* __restrict__ rh16, int tstep) {
  __shared__ __half2 sWzr[Cc * Hh];           // 20 KB: {wz, wr} per (c,o)
  __shared__ __align__(16) float sX[16][Cc];  // 5 KB
  const int tid = threadIdx.x;
  const int i0 = blockIdx.x * 16;
  for (int q = tid; q < Cc * Hh; q += 256)
    sWzr[q] = __floats2half2_rn(Wz[q], Wr[q]);
  const int wv = tid >> 6, lane = tid & 63;
  const int g = lane >> 4, c4 = lane & 15;
  const __half* Pxt = Px16 + (size_t)tstep * Nn * Ff;
  // phase A: wave-private gather of 4 nodes into sX rows (no barrier needed)
  for (int nd = 0; nd < 4; nd++) {
    int i = i0 + wv * 4 + nd;
    if (i >= Nn) break;
    int row = wv * 4 + nd;
    if (g == 1 && c4 < 4) {  // stage Px row (16 halves) via 4 lanes
      uint2 raw = *(const uint2*)(Pxt + (size_t)i * Ff + 4 * c4);
      float2 f01 = __half22float2(*reinterpret_cast<const __half2*>(&raw.x));
      float2 f23 = __half22float2(*reinterpret_cast<const __half2*>(&raw.y));
      *(float4*)&sX[row][4 * c4] = make_float4(f01.x, f01.y, f23.x, f23.y);
    }
    float d = dis[i];
    float a0, a1, a2, a3;
    gather64(h16, i, g, c4, rp, edge2, d * d, a0, a1, a2, a3);
    if (lane < 16) *(float4*)&sX[row][Ff + 4 * c4] = make_float4(a0, a1, a2, a3);
  }
  __syncthreads();
  // phase B: GEMM
  const int o = lane;
  float az[4] = {0, 0, 0, 0}, ar[4] = {0, 0, 0, 0};
  for (int c = 0; c < Cc; c += 4) {
    float2 w0 = __half22float2(sWzr[(c + 0) * Hh + o]);
    float2 w1 = __half22float2(sWzr[(c + 1) * Hh + o]);
    float2 w2 = __half22float2(sWzr[(c + 2) * Hh + o]);
    float2 w3 = __half22float2(sWzr[(c + 3) * Hh + o]);
#pragma unroll
    for (int nd = 0; nd < 4; nd++) {
      const float4 xv = *(const float4*)&sX[wv * 4 + nd][c];
      az[nd] = fmaf(xv.x, w0.x, fmaf(xv.y, w1.x, fmaf(xv.z, w2.x, fmaf(xv.w, w3.x, az[nd]))));
      ar[nd] = fmaf(xv.x, w0.y, fmaf(xv.y, w1.y, fmaf(xv.z, w2.y, fmaf(xv.w, w3.y, ar[nd]))));
    }
  }
  float bzo = bz[o], bro = br[o];
#pragma unroll
  for (int nd = 0; nd < 4; nd++) {
    int i = i0 + wv * 4 + nd;
    if (i < Nn) {
      float zv = sigmoidf_(az[nd] + bzo);
      float rv = sigmoidf_(ar[nd] + bro);
      float hv = __half2float(h16[(size_t)i * Hh + o]);
      zb16[(size_t)i * Hh + o] = __float2half(zv);
      rh16[(size_t)i * Hh + o] = __float2half(rv * hv);
    }
  }
}

// ---------------- fused: gather(rh16) + h GEMM + GRU update ----------------
__global__ __launch_bounds__(256) void k_h_f(
    const __half* __restrict__ Px16, const __half* __restrict__ rh16,
    const __half* __restrict__ zb16, float* __restrict__ h, __half* __restrict__ h16,
    __half* __restrict__ hs16,
    const int* __restrict__ rp, const int2* __restrict__ edge2,
    const float* __restrict__ dis,
    const float* __restrict__ Wh, const float* __restrict__ bh, int tstep) {
  __shared__ float sWh[Cc * Hh];              // 20 KB fp32
  __shared__ __align__(16) float sX[16][Cc];  // 5 KB
  const int tid = threadIdx.x;
  const int i0 = blockIdx.x * 16;
  {
    const float4* w4 = (const float4*)Wh;
    float4* s4 = (float4*)sWh;
    for (int q = tid; q < (Cc * Hh) / 4; q += 256) s4[q] = w4[q];
  }
  const int wv = tid >> 6, lane = tid & 63;
  const int g = lane >> 4, c4 = lane & 15;
  const __half* Pxt = Px16 + (size_t)tstep * Nn * Ff;
  for (int nd = 0; nd < 4; nd++) {
    int i = i0 + wv * 4 + nd;
    if (i >= Nn) break;
    int row = wv * 4 + nd;
    if (g == 1 && c4 < 4) {
      uint2 raw = *(const uint2*)(Pxt + (size_t)i * Ff + 4 * c4);
      float2 f01 = __half22float2(*reinterpret_cast<const __half2*>(&raw.x));
      float2 f23 = __half22float2(*reinterpret_cast<const __half2*>(&raw.y));
      *(float4*)&sX[row][4 * c4] = make_float4(f01.x, f01.y, f23.x, f23.y);
    }
    float d = dis[i];
    float a0, a1, a2, a3;
    gather64(rh16, i, g, c4, rp, edge2, d * d, a0, a1, a2, a3);
    if (lane < 16) *(float4*)&sX[row][Ff + 4 * c4] = make_float4(a0, a1, a2, a3);
  }
  __syncthreads();
  const int o = lane;
  float ah[4] = {0, 0, 0, 0};
  for (int c = 0; c < Cc; c += 4) {
    float w0 = sWh[(c + 0) * Hh + o], w1 = sWh[(c + 1) * Hh + o];
    float w2 = sWh[(c + 2) * Hh + o], w3 = sWh[(c + 3) * Hh + o];
#pragma unroll
    for (int nd = 0; nd < 4; nd++) {
      const float4 xv = *(const float4*)&sX[wv * 4 + nd][c];
      ah[nd] = fmaf(xv.x, w0, fmaf(xv.y, w1, fmaf(xv.z, w2, fmaf(xv.w, w3, ah[nd]))));
    }
  }
  float bho = bh[o];
  __half* hst = hs16 + (size_t)tstep * Nn * Hh;
#pragma unroll
  for (int nd = 0; nd < 4; nd++) {
    int i = i0 + wv * 4 + nd;
    if (i < Nn) {
      float hc = tanhf(ah[nd] + bho);
      float zv = __half2float(zb16[(size_t)i * Hh + o]);
      float hv = h[(size_t)i * Hh + o];
      float hn = zv * hv + (1.0f - zv) * hc;
      h[(size_t)i * Hh + o] = hn;
      __half hh = __float2half(hn);
      h16[(size_t)i * Hh + o] = hh;
      hst[(size_t)i * Hh + o] = hh;
    }
  }
}

// ---------------- attention + output: wave per node over T=12 history ----------------
// Wa loads hoisted out of the t-loop: 4 LDS reads serve 12 t (12x fewer ds_read_b32).
__global__ __launch_bounds__(256) void k_att(
    const __half* __restrict__ hs16, const float* __restrict__ Wa,
    const float* __restrict__ ba, const float* __restrict__ cv,
    const float* __restrict__ Wfc, const float* __restrict__ bfc,
    float* __restrict__ out) {
  __shared__ float sWa[Hh * Hh];                  // 16 KB
  __shared__ __align__(16) float sH[4][Tt][Hh];   // 12 KB
  const int tid = threadIdx.x;
  {
    const float4* a4 = (const float4*)Wa;
    float4* sa4 = (float4*)sWa;
    for (int q = tid; q < (Hh * Hh) / 4; q += 256) sa4[q] = a4[q];
  }
  const int wv = tid >> 6, o = tid & 63;
  const int i = blockIdx.x * 4 + wv;
  if (i < Nn) {
#pragma unroll
    for (int t = 0; t < Tt; t++)
      sH[wv][t][o] = __half2float(hs16[(size_t)t * Nn * Hh + (size_t)i * Hh + o]);
  }
  __syncthreads();
  if (i >= Nn) return;
  float al[Tt];
#pragma unroll
  for (int t = 0; t < Tt; t++) al[t] = 0.f;
  for (int c = 0; c < Hh; c += 4) {
    float w0 = sWa[(c + 0) * Hh + o], w1 = sWa[(c + 1) * Hh + o];
    float w2 = sWa[(c + 2) * Hh + o], w3 = sWa[(c + 3) * Hh + o];
#pragma unroll
    for (int t = 0; t < Tt; t++) {
      const float4 hv4 = *(const float4*)&sH[wv][t][c];
      al[t] = fmaf(hv4.x, w0, fmaf(hv4.y, w1, fmaf(hv4.z, w2, fmaf(hv4.w, w3, al[t]))));
    }
  }
  float bao = ba[o], cvo = cv[o];
#pragma unroll
  for (int t = 0; t < Tt; t++) {
    float ap = tanhf(al[t] + bao) * cvo;
#pragma unroll
    for (int off = 32; off >= 1; off >>= 1) ap += __shfl_xor(ap, off, 64);
    al[t] = ap;  // all lanes hold align[i][t]
  }
  float m = al[0];
#pragma unroll
  for (int t = 1; t < Tt; t++) m = fmaxf(m, al[t]);
  float s = 0.f;
#pragma unroll
  for (int t = 0; t < Tt; t++) { al[t] = expf(al[t] - m); s += al[t]; }
  float inv = 1.0f / s;
  float cx = 0.f;
#pragma unroll
  for (int t = 0; t < Tt; t++) cx = fmaf(al[t], sH[wv][t][o], cx);
  float p = cx * inv * Wfc[o];
#pragma unroll
  for (int off = 32; off >= 1; off >>= 1) p += __shfl_xor(p, off, 64);
  if (o == 0) out[i] = p + bfc[0];
}

extern "C" void kernel_launch(void* const* d_in, const int* in_sizes, int n_in,
                              void* d_out, int out_size, void* d_ws, size_t ws_size,
                              hipStream_t stream) {
  const float* x   = (const float*)d_in[0];
  const int* ei    = (const int*)d_in[1];
  const float* ew  = (const float*)d_in[2];
  const float* Wz  = (const float*)d_in[3];
  const float* bz  = (const float*)d_in[4];
  const float* Wr  = (const float*)d_in[5];
  const float* br  = (const float*)d_in[6];
  const float* Wh  = (const float*)d_in[7];
  const float* bh  = (const float*)d_in[8];
  const float* Wa  = (const float*)d_in[9];
  const float* ba  = (const float*)d_in[10];
  const float* cv  = (const float*)d_in[11];
  const float* Wfc = (const float*)d_in[12];
  const float* bfc = (const float*)d_in[13];
  float* out = (float*)d_out;

  char* w = (char*)d_ws;
  auto alloc = [&](size_t bytes) {
    char* p = w;
    w += (bytes + 255) & ~(size_t)255;
    return p;
  };
  unsigned long long* dc = (unsigned long long*)alloc((size_t)Nn * 8);
  float* dis = (float*)alloc((size_t)Nn * 4);
  int* cnt   = (int*)alloc((size_t)Nn * 4);
  int* rp    = (int*)alloc((size_t)(Nn + 1) * 4);
  int* cur   = (int*)alloc((size_t)Nn * 4);
  int2* edge2 = (int2*)alloc((size_t)Ee * 8);
  __half* x16  = (__half*)alloc((size_t)Nn * Ff * Tt * 2);
  __half* Px16 = (__half*)alloc((size_t)Tt * Nn * Ff * 2);
  float* h     = (float*)alloc((size_t)Nn * Hh * 4);
  __half* h16  = (__half*)alloc((size_t)Nn * Hh * 2);
  __half* rh16 = (__half*)alloc((size_t)Nn * Hh * 2);
  __half* zb16 = (__half*)alloc((size_t)Nn * Hh * 2);
  __half* hs16 = (__half*)alloc((size_t)Tt * Nn * Hh * 2);  // 76.8 MB history

  hipMemsetAsync(dc, 0, (size_t)Nn * 8, stream);
  hipMemsetAsync(h, 0, (size_t)Nn * Hh * 4, stream);
  hipMemsetAsync(h16, 0, (size_t)Nn * Hh * 2, stream);  // fp16 zero == 0x0000

  k_deg<<<(Ee + 255) / 256, 256, 0, stream>>>(ei, ew, dc);
  k_dis<<<(Nn + 255) / 256, 256, 0, stream>>>(dc, dis, cnt);
  k_scan<<<1, 1024, 0, stream>>>(cnt, rp, cur);
  k_scatter<<<(Ee + 255) / 256, 256, 0, stream>>>(ei, ew, dis, cur, edge2);
  {
    const size_t total = (size_t)Nn * Ff * Tt;
    k_cvt_x<<<(int)((total + 255) / 256), 256, 0, stream>>>(x, x16);
  }
  k_agg_px<<<(Nn + 3) / 4, 256, 0, stream>>>(x, x16, Px16, rp, edge2, dis);

  const int gGemm = (Nn + 15) / 16;  // 256-thread blocks, 16 nodes each
  const int gNode = (Nn + 3) / 4;
  for (int t = 0; t < Tt; t++) {
    k_zr_f<<<gGemm, 256, 0, stream>>>(Px16, h16, rp, edge2, dis, Wz, bz, Wr, br,
                                      zb16, rh16, t);
    k_h_f<<<gGemm, 256, 0, stream>>>(Px16, rh16, zb16, h, h16, hs16, rp, edge2, dis,
                                     Wh, bh, t);
  }
  k_att<<<gNode, 256, 0, stream>>>(hs16, Wa, ba, cv, Wfc, bfc, out);
}

// Round 9
// 3387.362 us; speedup vs baseline: 1.7504x; 1.7504x over previous
//
#include <hip/hip_runtime.h>
#include <hip/hip_fp16.h>
#include <math.h>

#define Nn 50000
#define Ff 16
#define Tt 12
#define Hh 64
#define Ee 1600000
#define Cc 80  // F + H

static __device__ __forceinline__ float sigmoidf_(float x) { return 1.0f / (1.0f + expf(-x)); }

// ---------------- CSR build ----------------
// dc[d] accumulates (count << 42) + round(ew * 2^21) in one u64 atomic.
__global__ void k_deg(const int* __restrict__ ei, const float* __restrict__ ew,
                      unsigned long long* __restrict__ dc) {
  int e = blockIdx.x * blockDim.x + threadIdx.x;
  if (e >= Ee) return;
  int d = ei[Ee + e];
  unsigned long long pk = (1ULL << 42) + (unsigned long long)(ew[e] * 2097152.0f + 0.5f);
  atomicAdd(&dc[d], pk);
}

__global__ void k_dis(const unsigned long long* __restrict__ dc,
                      float* __restrict__ dis, int* __restrict__ cnt) {
  int i = blockIdx.x * blockDim.x + threadIdx.x;
  if (i >= Nn) return;
  unsigned long long v = dc[i];
  cnt[i] = (int)(v >> 42);
  float deg = (float)(v & ((1ULL << 42) - 1)) * (1.0f / 2097152.0f);
  dis[i] = 1.0f / sqrtf(deg + 1.0f);
}

__global__ __launch_bounds__(1024) void k_scan(const int* __restrict__ cnt,
                                               int* __restrict__ rp, int* __restrict__ cur) {
  __shared__ int ss[1024];
  const int ITEMS = (Nn + 1023) / 1024;  // 49
  int t = threadIdx.x;
  int base = t * ITEMS;
  int sum = 0;
  for (int k = 0; k < ITEMS; k++) {
    int idx = base + k;
    if (idx < Nn) sum += cnt[idx];
  }
  ss[t] = sum;
  __syncthreads();
  for (int off = 1; off < 1024; off <<= 1) {
    int v = (t >= off) ? ss[t - off] : 0;
    __syncthreads();
    ss[t] += v;
    __syncthreads();
  }
  int run = ss[t] - sum;  // exclusive prefix
  for (int k = 0; k < ITEMS; k++) {
    int idx = base + k;
    if (idx < Nn) { rp[idx] = run; cur[idx] = run; run += cnt[idx]; }
  }
  if (t == 0) rp[Nn] = Ee;
}

// edge2[pos] = {src, normalized weight}: one scattered 8-B store per edge
__global__ void k_scatter(const int* __restrict__ ei, const float* __restrict__ ew,
                          const float* __restrict__ dis, int* __restrict__ cur,
                          int2* __restrict__ edge2) {
  int e = blockIdx.x * blockDim.x + threadIdx.x;
  if (e >= Ee) return;
  int s = ei[e];
  int d = ei[Ee + e];
  float w = ew[e] * dis[s] * dis[d];
  int pos = atomicAdd(&cur[d], 1);
  edge2[pos] = make_int2(s, __float_as_int(w));
}

// ---------------- x fp32 -> fp16 (once) ----------------
__global__ void k_cvt_x(const float* __restrict__ x, __half* __restrict__ x16) {
  size_t idx = (size_t)blockIdx.x * blockDim.x + threadIdx.x;
  const size_t total = (size_t)Nn * Ff * Tt;
  if (idx < total) x16[idx] = __float2half(x[idx]);
}

// ---------------- Px16[t][i][f] = (A_hat @ x): wave per node, 48 lanes x 8B per edge ----------------
__global__ __launch_bounds__(256) void k_agg_px(
    const float* __restrict__ x, const __half* __restrict__ x16, __half* __restrict__ Px16,
    const int* __restrict__ rp, const int2* __restrict__ edge2,
    const float* __restrict__ dis) {
  int i = blockIdx.x * 4 + (threadIdx.x >> 6);
  if (i >= Nn) return;
  int lane = threadIdx.x & 63;
  const int R = Ff * Tt;  // 192
  const bool act = lane < 48;
  float d = dis[i], sn = d * d;
  float a0 = 0.f, a1 = 0.f, a2 = 0.f, a3 = 0.f;
  if (act) {
    float4 sv = *(const float4*)(x + (size_t)i * R + 4 * lane);  // self, fp32 exact
    a0 = sn * sv.x; a1 = sn * sv.y; a2 = sn * sv.z; a3 = sn * sv.w;
  }
  int jb = rp[i], je = rp[i + 1];
  for (int j = jb; j < je; j += 2) {
    int jc1 = min(j + 1, Ee - 1);
    int2 e0 = edge2[j];
    int2 e1 = edge2[jc1];
    float w0 = __int_as_float(e0.y);
    float w1 = (j + 1 < je) ? __int_as_float(e1.y) : 0.f;
    if (act) {
      uint2 g0 = *(const uint2*)(x16 + (size_t)e0.x * R + 4 * lane);
      uint2 g1 = *(const uint2*)(x16 + (size_t)e1.x * R + 4 * lane);
      float2 p01 = __half22float2(*reinterpret_cast<const __half2*>(&g0.x));
      float2 p23 = __half22float2(*reinterpret_cast<const __half2*>(&g0.y));
      float2 q01 = __half22float2(*reinterpret_cast<const __half2*>(&g1.x));
      float2 q23 = __half22float2(*reinterpret_cast<const __half2*>(&g1.y));
      a0 = fmaf(w0, p01.x, a0); a1 = fmaf(w0, p01.y, a1);
      a2 = fmaf(w0, p23.x, a2); a3 = fmaf(w0, p23.y, a3);
      a0 = fmaf(w1, q01.x, a0); a1 = fmaf(w1, q01.y, a1);
      a2 = fmaf(w1, q23.x, a2); a3 = fmaf(w1, q23.y, a3);
    }
  }
  if (act) {
#pragma unroll
    for (int k = 0; k < 4; k++) {
      int cch = 4 * lane + k;           // channel = f*T + t
      int f = cch / Tt, tt = cch % Tt;
      float val = (k == 0) ? a0 : (k == 1) ? a1 : (k == 2) ? a2 : a3;
      Px16[(size_t)tt * Nn * Ff + (size_t)i * Ff + f] = __float2half(val);
    }
  }
}

// ---------------- aggregation: wave per node, 16 lanes/edge x 8B, 4 edges/instr ----------------
__global__ __launch_bounds__(256) void k_agg64v(
    const __half* __restrict__ v, __half* __restrict__ outv,
    const int* __restrict__ rp, const int2* __restrict__ edge2,
    const float* __restrict__ dis) {
  int i = blockIdx.x * 4 + (threadIdx.x >> 6);
  if (i >= Nn) return;
  int lane = threadIdx.x & 63;
  int g = lane >> 4;   // edge slot 0..3
  int c = lane & 15;   // channel quad: 4c..4c+3
  float d = dis[i], sn = d * d;
  float a0, a1, a2, a3;
  {
    const uint2 gv = *(const uint2*)(v + (size_t)i * Hh + 4 * c);  // self
    float2 f01 = __half22float2(*reinterpret_cast<const __half2*>(&gv.x));
    float2 f23 = __half22float2(*reinterpret_cast<const __half2*>(&gv.y));
    float ws = (g == 0) ? sn : 0.f;
    a0 = ws * f01.x; a1 = ws * f01.y; a2 = ws * f23.x; a3 = ws * f23.y;
  }
  int jb = rp[i], je = rp[i + 1];
  for (int j0 = jb; j0 < je; j0 += 8) {
    int j1 = j0 + g;
    int j2 = j0 + 4 + g;
    int2 e1 = edge2[min(j1, Ee - 1)];
    int2 e2 = edge2[min(j2, Ee - 1)];
    float w1 = (j1 < je) ? __int_as_float(e1.y) : 0.f;
    float w2 = (j2 < je) ? __int_as_float(e2.y) : 0.f;
    const uint2 g1 = *(const uint2*)(v + (size_t)e1.x * Hh + 4 * c);
    const uint2 g2 = *(const uint2*)(v + (size_t)e2.x * Hh + 4 * c);
    float2 p01 = __half22float2(*reinterpret_cast<const __half2*>(&g1.x));
    float2 p23 = __half22float2(*reinterpret_cast<const __half2*>(&g1.y));
    float2 q01 = __half22float2(*reinterpret_cast<const __half2*>(&g2.x));
    float2 q23 = __half22float2(*reinterpret_cast<const __half2*>(&g2.y));
    a0 = fmaf(w1, p01.x, a0); a1 = fmaf(w1, p01.y, a1);
    a2 = fmaf(w1, p23.x, a2); a3 = fmaf(w1, p23.y, a3);
    a0 = fmaf(w2, q01.x, a0); a1 = fmaf(w2, q01.y, a1);
    a2 = fmaf(w2, q23.x, a2); a3 = fmaf(w2, q23.y, a3);
  }
  a0 += __shfl_xor(a0, 16, 64); a1 += __shfl_xor(a1, 16, 64);
  a2 += __shfl_xor(a2, 16, 64); a3 += __shfl_xor(a3, 16, 64);
  a0 += __shfl_xor(a0, 32, 64); a1 += __shfl_xor(a1, 32, 64);
  a2 += __shfl_xor(a2, 32, 64); a3 += __shfl_xor(a3, 32, 64);
  if (lane < 16) {
    __half2 h01, h23;
    h01.x = __float2half_rn(a0); h01.y = __float2half_rn(a1);
    h23.x = __float2half_rn(a2); h23.y = __float2half_rn(a3);
    uint2 st;
    st.x = *reinterpret_cast<unsigned int*>(&h01);
    st.y = *reinterpret_cast<unsigned int*>(&h23);
    *(uint2*)(outv + (size_t)i * Hh + 4 * c) = st;
  }
}

// shared helper: stage 16 nodes x 80 channels (fp16 sources) into fp32 LDS
static __device__ __forceinline__ void stage_x(
    float (*sX)[Cc], const __half* __restrict__ Px16t, const __half* __restrict__ P64,
    int i0, int tid) {
  if (tid < 160) {
    int n = tid / 10, r = tid % 10;
    int i = i0 + n;
    uint4 raw = make_uint4(0u, 0u, 0u, 0u);
    if (i < Nn) {
      raw = (r < 2) ? *(const uint4*)(Px16t + (size_t)i * Ff + r * 8)
                    : *(const uint4*)(P64 + (size_t)i * Hh + (r - 2) * 8);
    }
    float2 f0 = __half22float2(*reinterpret_cast<const __half2*>(&raw.x));
    float2 f1 = __half22float2(*reinterpret_cast<const __half2*>(&raw.y));
    float2 f2 = __half22float2(*reinterpret_cast<const __half2*>(&raw.z));
    float2 f3 = __half22float2(*reinterpret_cast<const __half2*>(&raw.w));
    float* dst = &sX[n][r * 8];
    dst[0] = f0.x; dst[1] = f0.y; dst[2] = f1.x; dst[3] = f1.y;
    dst[4] = f2.x; dst[5] = f2.y; dst[6] = f3.x; dst[7] = f3.y;
  }
}

// ---------------- GEMM z/r: 256 threads, 4 waves, 16 nodes/block ----------------
// NOTE: no waves-per-EU hint — on this toolchain the 2nd __launch_bounds__ arg
// forces a VGPR cap the compiler satisfies by spilling to scratch (GB-scale
// WRITE_SIZE, 10-30x dur). Measured rounds 2/6.
__global__ __launch_bounds__(256) void k_gemm_zr(
    const __half* __restrict__ Px16, const __half* __restrict__ Ph16,
    const __half* __restrict__ h16,
    const float* __restrict__ Wz, const float* __restrict__ bz,
    const float* __restrict__ Wr, const float* __restrict__ br,
    __half* __restrict__ zb16, __half* __restrict__ rh16, int tstep) {
  __shared__ float sWz[Cc * Hh];    // 20 KB
  __shared__ float sWr[Cc * Hh];    // 20 KB
  __shared__ float sX[16][Cc];      // 5 KB
  const int tid = threadIdx.x;
  const int i0 = blockIdx.x * 16;
  {
    const float4* wz4 = (const float4*)Wz;
    const float4* wr4 = (const float4*)Wr;
    float4* sz4 = (float4*)sWz;
    float4* sr4 = (float4*)sWr;
    for (int q = tid; q < (Cc * Hh) / 4; q += 256) { sz4[q] = wz4[q]; sr4[q] = wr4[q]; }
  }
  stage_x(sX, Px16 + (size_t)tstep * Nn * Ff, Ph16, i0, tid);
  __syncthreads();
  const int wv = tid >> 6, o = tid & 63;
  float az[4] = {0, 0, 0, 0}, ar[4] = {0, 0, 0, 0};
  for (int c = 0; c < Cc; c += 4) {
    float z0 = sWz[(c + 0) * Hh + o], z1 = sWz[(c + 1) * Hh + o];
    float z2 = sWz[(c + 2) * Hh + o], z3 = sWz[(c + 3) * Hh + o];
    float r0 = sWr[(c + 0) * Hh + o], r1 = sWr[(c + 1) * Hh + o];
    float r2 = sWr[(c + 2) * Hh + o], r3 = sWr[(c + 3) * Hh + o];
#pragma unroll
    for (int nd = 0; nd < 4; nd++) {
      const float4 xv = *(const float4*)&sX[wv * 4 + nd][c];
      az[nd] = fmaf(xv.x, z0, fmaf(xv.y, z1, fmaf(xv.z, z2, fmaf(xv.w, z3, az[nd]))));
      ar[nd] = fmaf(xv.x, r0, fmaf(xv.y, r1, fmaf(xv.z, r2, fmaf(xv.w, r3, ar[nd]))));
    }
  }
  float bzo = bz[o], bro = br[o];
#pragma unroll
  for (int nd = 0; nd < 4; nd++) {
    int i = i0 + wv * 4 + nd;
    if (i < Nn) {
      float zv = sigmoidf_(az[nd] + bzo);
      float rv = sigmoidf_(ar[nd] + bro);
      float hv = __half2float(h16[(size_t)i * Hh + o]);
      zb16[(size_t)i * Hh + o] = __float2half(zv);
      rh16[(size_t)i * Hh + o] = __float2half(rv * hv);
    }
  }
}

// ---------------- GEMM h: GRU update; writes h (fp32), h16, hs16[t] ----------------
__global__ __launch_bounds__(256) void k_gemm_h(
    const __half* __restrict__ Px16, const __half* __restrict__ Prh16,
    const __half* __restrict__ zb16, float* __restrict__ h, __half* __restrict__ h16,
    __half* __restrict__ hs16,
    const float* __restrict__ Wh, const float* __restrict__ bh, int tstep) {
  __shared__ float sWh[Cc * Hh];    // 20 KB
  __shared__ float sX[16][Cc];      // 5 KB
  const int tid = threadIdx.x;
  const int i0 = blockIdx.x * 16;
  {
    const float4* w4 = (const float4*)Wh;
    float4* s4 = (float4*)sWh;
    for (int q = tid; q < (Cc * Hh) / 4; q += 256) s4[q] = w4[q];
  }
  stage_x(sX, Px16 + (size_t)tstep * Nn * Ff, Prh16, i0, tid);
  __syncthreads();
  const int wv = tid >> 6, o = tid & 63;
  float ah[4] = {0, 0, 0, 0};
  for (int c = 0; c < Cc; c += 4) {
    float w0 = sWh[(c + 0) * Hh + o], w1 = sWh[(c + 1) * Hh + o];
    float w2 = sWh[(c + 2) * Hh + o], w3 = sWh[(c + 3) * Hh + o];
#pragma unroll
    for (int nd = 0; nd < 4; nd++) {
      const float4 xv = *(const float4*)&sX[wv * 4 + nd][c];
      ah[nd] = fmaf(xv.x, w0, fmaf(xv.y, w1, fmaf(xv.z, w2, fmaf(xv.w, w3, ah[nd]))));
    }
  }
  float bho = bh[o];
  __half* hst = hs16 + (size_t)tstep * Nn * Hh;
#pragma unroll
  for (int nd = 0; nd < 4; nd++) {
    int i = i0 + wv * 4 + nd;
    if (i < Nn) {
      float hc = tanhf(ah[nd] + bho);
      float zv = __half2float(zb16[(size_t)i * Hh + o]);
      float hv = h[(size_t)i * Hh + o];
      float hn = zv * hv + (1.0f - zv) * hc;
      h[(size_t)i * Hh + o] = hn;
      __half hh = __float2half(hn);
      h16[(size_t)i * Hh + o] = hh;
      hst[(size_t)i * Hh + o] = hh;
    }
  }
}

// ---------------- attention + output: wave per node over T=12 history ----------------
// t-tiled (TB=4) loop interchange: Wa LDS reads cut 4x vs round-7 while keeping
// only 4 live accumulators (round-8's 12-acc interchange spilled: VGPR 256, 3.6 GB scratch).
__global__ __launch_bounds__(256) void k_att(
    const __half* __restrict__ hs16, const float* __restrict__ Wa,
    const float* __restrict__ ba, const float* __restrict__ cv,
    const float* __restrict__ Wfc, const float* __restrict__ bfc,
    float* __restrict__ out) {
  __shared__ float sWa[Hh * Hh];                  // 16 KB
  __shared__ __align__(16) float sH[4][Tt][Hh];   // 12 KB
  const int tid = threadIdx.x;
  {
    const float4* a4 = (const float4*)Wa;
    float4* sa4 = (float4*)sWa;
    for (int q = tid; q < (Hh * Hh) / 4; q += 256) sa4[q] = a4[q];
  }
  const int wv = tid >> 6, o = tid & 63;
  const int i = blockIdx.x * 4 + wv;
  if (i < Nn) {
#pragma unroll
    for (int t = 0; t < Tt; t++)
      sH[wv][t][o] = __half2float(hs16[(size_t)t * Nn * Hh + (size_t)i * Hh + o]);
  }
  __syncthreads();
  if (i >= Nn) return;
  float bao = ba[o], cvo = cv[o];
  float al[Tt];
  for (int t0 = 0; t0 < Tt; t0 += 4) {
    float s0 = 0.f, s1 = 0.f, s2 = 0.f, s3 = 0.f;
    for (int c = 0; c < Hh; c += 4) {
      float w0 = sWa[(c + 0) * Hh + o], w1 = sWa[(c + 1) * Hh + o];
      float w2 = sWa[(c + 2) * Hh + o], w3 = sWa[(c + 3) * Hh + o];
      const float4 h0 = *(const float4*)&sH[wv][t0 + 0][c];
      const float4 h1 = *(const float4*)&sH[wv][t0 + 1][c];
      const float4 h2 = *(const float4*)&sH[wv][t0 + 2][c];
      const float4 h3 = *(const float4*)&sH[wv][t0 + 3][c];
      s0 = fmaf(h0.x, w0, fmaf(h0.y, w1, fmaf(h0.z, w2, fmaf(h0.w, w3, s0))));
      s1 = fmaf(h1.x, w0, fmaf(h1.y, w1, fmaf(h1.z, w2, fmaf(h1.w, w3, s1))));
      s2 = fmaf(h2.x, w0, fmaf(h2.y, w1, fmaf(h2.z, w2, fmaf(h2.w, w3, s2))));
      s3 = fmaf(h3.x, w0, fmaf(h3.y, w1, fmaf(h3.z, w2, fmaf(h3.w, w3, s3))));
    }
#pragma unroll
    for (int k = 0; k < 4; k++) {
      float sv = (k == 0) ? s0 : (k == 1) ? s1 : (k == 2) ? s2 : s3;
      float ap = tanhf(sv + bao) * cvo;
#pragma unroll
      for (int off = 32; off >= 1; off >>= 1) ap += __shfl_xor(ap, off, 64);
      al[t0 + k] = ap;  // all lanes hold align[i][t]
    }
  }
  float m = al[0];
#pragma unroll
  for (int t = 1; t < Tt; t++) m = fmaxf(m, al[t]);
  float s = 0.f;
#pragma unroll
  for (int t = 0; t < Tt; t++) { al[t] = expf(al[t] - m); s += al[t]; }
  float inv = 1.0f / s;
  float cx = 0.f;
#pragma unroll
  for (int t = 0; t < Tt; t++) cx = fmaf(al[t], sH[wv][t][o], cx);
  float p = cx * inv * Wfc[o];
#pragma unroll
  for (int off = 32; off >= 1; off >>= 1) p += __shfl_xor(p, off, 64);
  if (o == 0) out[i] = p + bfc[0];
}

extern "C" void kernel_launch(void* const* d_in, const int* in_sizes, int n_in,
                              void* d_out, int out_size, void* d_ws, size_t ws_size,
                              hipStream_t stream) {
  const float* x   = (const float*)d_in[0];
  const int* ei    = (const int*)d_in[1];
  const float* ew  = (const float*)d_in[2];
  const float* Wz  = (const float*)d_in[3];
  const float* bz  = (const float*)d_in[4];
  const float* Wr  = (const float*)d_in[5];
  const float* br  = (const float*)d_in[6];
  const float* Wh  = (const float*)d_in[7];
  const float* bh  = (const float*)d_in[8];
  const float* Wa  = (const float*)d_in[9];
  const float* ba  = (const float*)d_in[10];
  const float* cv  = (const float*)d_in[11];
  const float* Wfc = (const float*)d_in[12];
  const float* bfc = (const float*)d_in[13];
  float* out = (float*)d_out;

  char* w = (char*)d_ws;
  auto alloc = [&](size_t bytes) {
    char* p = w;
    w += (bytes + 255) & ~(size_t)255;
    return p;
  };
  unsigned long long* dc = (unsigned long long*)alloc((size_t)Nn * 8);
  float* dis = (float*)alloc((size_t)Nn * 4);
  int* cnt   = (int*)alloc((size_t)Nn * 4);
  int* rp    = (int*)alloc((size_t)(Nn + 1) * 4);
  int* cur   = (int*)alloc((size_t)Nn * 4);
  int2* edge2 = (int2*)alloc((size_t)Ee * 8);
  __half* x16  = (__half*)alloc((size_t)Nn * Ff * Tt * 2);
  __half* Px16 = (__half*)alloc((size_t)Tt * Nn * Ff * 2);
  float* h     = (float*)alloc((size_t)Nn * Hh * 4);
  __half* h16  = (__half*)alloc((size_t)Nn * Hh * 2);
  __half* rh16 = (__half*)alloc((size_t)Nn * Hh * 2);
  __half* zb16 = (__half*)alloc((size_t)Nn * Hh * 2);
  __half* Ph16 = (__half*)alloc((size_t)Nn * Hh * 2);
  __half* Prh16 = (__half*)alloc((size_t)Nn * Hh * 2);
  __half* hs16 = (__half*)alloc((size_t)Tt * Nn * Hh * 2);  // 76.8 MB history

  hipMemsetAsync(dc, 0, (size_t)Nn * 8, stream);
  hipMemsetAsync(h, 0, (size_t)Nn * Hh * 4, stream);
  hipMemsetAsync(h16, 0, (size_t)Nn * Hh * 2, stream);  // fp16 zero == 0x0000

  k_deg<<<(Ee + 255) / 256, 256, 0, stream>>>(ei, ew, dc);
  k_dis<<<(Nn + 255) / 256, 256, 0, stream>>>(dc, dis, cnt);
  k_scan<<<1, 1024, 0, stream>>>(cnt, rp, cur);
  k_scatter<<<(Ee + 255) / 256, 256, 0, stream>>>(ei, ew, dis, cur, edge2);
  {
    const size_t total = (size_t)Nn * Ff * Tt;
    k_cvt_x<<<(int)((total + 255) / 256), 256, 0, stream>>>(x, x16);
  }
  k_agg_px<<<(Nn + 3) / 4, 256, 0, stream>>>(x, x16, Px16, rp, edge2, dis);

  const int gGemm = (Nn + 15) / 16;  // 256-thread blocks, 16 nodes each
  const int gNode = (Nn + 3) / 4;
  for (int t = 0; t < Tt; t++) {
    k_agg64v<<<gNode, 256, 0, stream>>>(h16, Ph16, rp, edge2, dis);
    k_gemm_zr<<<gGemm, 256, 0, stream>>>(Px16, Ph16, h16, Wz, bz, Wr, br, zb16, rh16, t);
    k_agg64v<<<gNode, 256, 0, stream>>>(rh16, Prh16, rp, edge2, dis);
    k_gemm_h<<<gGemm, 256, 0, stream>>>(Px16, Prh16, zb16, h, h16, hs16, Wh, bh, t);
  }
  k_att<<<gNode, 256, 0, stream>>>(hs16, Wa, ba, cv, Wfc, bfc, out);
}

// Round 10
// 2707.295 us; speedup vs baseline: 2.1901x; 1.2512x over previous
//
#include <hip/hip_runtime.h>
#include <hip/hip_fp16.h>
#include <math.h>

#define Nn 50000
#define Ff 16
#define Tt 12
#define Hh 64
#define Ee 1600000
#define Cc 80  // F + H

static __device__ __forceinline__ float sigmoidf_(float x) { return 1.0f / (1.0f + expf(-x)); }

// ---------------- CSR build ----------------
// dc[d] accumulates (count << 42) + round(ew * 2^21) in one u64 atomic.
__global__ void k_deg(const int* __restrict__ ei, const float* __restrict__ ew,
                      unsigned long long* __restrict__ dc) {
  int e = blockIdx.x * blockDim.x + threadIdx.x;
  if (e >= Ee) return;
  int d = ei[Ee + e];
  unsigned long long pk = (1ULL << 42) + (unsigned long long)(ew[e] * 2097152.0f + 0.5f);
  atomicAdd(&dc[d], pk);
}

__global__ void k_dis(const unsigned long long* __restrict__ dc,
                      float* __restrict__ dis, int* __restrict__ cnt) {
  int i = blockIdx.x * blockDim.x + threadIdx.x;
  if (i >= Nn) return;
  unsigned long long v = dc[i];
  cnt[i] = (int)(v >> 42);
  float deg = (float)(v & ((1ULL << 42) - 1)) * (1.0f / 2097152.0f);
  dis[i] = 1.0f / sqrtf(deg + 1.0f);
}

__global__ __launch_bounds__(1024) void k_scan(const int* __restrict__ cnt,
                                               int* __restrict__ rp, int* __restrict__ cur) {
  __shared__ int ss[1024];
  const int ITEMS = (Nn + 1023) / 1024;  // 49
  int t = threadIdx.x;
  int base = t * ITEMS;
  int sum = 0;
  for (int k = 0; k < ITEMS; k++) {
    int idx = base + k;
    if (idx < Nn) sum += cnt[idx];
  }
  ss[t] = sum;
  __syncthreads();
  for (int off = 1; off < 1024; off <<= 1) {
    int v = (t >= off) ? ss[t - off] : 0;
    __syncthreads();
    ss[t] += v;
    __syncthreads();
  }
  int run = ss[t] - sum;  // exclusive prefix
  for (int k = 0; k < ITEMS; k++) {
    int idx = base + k;
    if (idx < Nn) { rp[idx] = run; cur[idx] = run; run += cnt[idx]; }
  }
  if (t == 0) rp[Nn] = Ee;
}

// edge2[pos] = {src, normalized weight}: one scattered 8-B store per edge
__global__ void k_scatter(const int* __restrict__ ei, const float* __restrict__ ew,
                          const float* __restrict__ dis, int* __restrict__ cur,
                          int2* __restrict__ edge2) {
  int e = blockIdx.x * blockDim.x + threadIdx.x;
  if (e >= Ee) return;
  int s = ei[e];
  int d = ei[Ee + e];
  float w = ew[e] * dis[s] * dis[d];
  int pos = atomicAdd(&cur[d], 1);
  edge2[pos] = make_int2(s, __float_as_int(w));
}

// ---------------- x fp32 -> fp16 (once) ----------------
__global__ void k_cvt_x(const float* __restrict__ x, __half* __restrict__ x16) {
  size_t idx = (size_t)blockIdx.x * blockDim.x + threadIdx.x;
  const size_t total = (size_t)Nn * Ff * Tt;
  if (idx < total) x16[idx] = __float2half(x[idx]);
}

// ---------------- Px16[t][i][f] = (A_hat @ x): wave per node, 48 lanes x 8B per edge ----------------
__global__ __launch_bounds__(256) void k_agg_px(
    const float* __restrict__ x, const __half* __restrict__ x16, __half* __restrict__ Px16,
    const int* __restrict__ rp, const int2* __restrict__ edge2,
    const float* __restrict__ dis) {
  int i = blockIdx.x * 4 + (threadIdx.x >> 6);
  if (i >= Nn) return;
  int lane = threadIdx.x & 63;
  const int R = Ff * Tt;  // 192
  const bool act = lane < 48;
  float d = dis[i], sn = d * d;
  float a0 = 0.f, a1 = 0.f, a2 = 0.f, a3 = 0.f;
  if (act) {
    float4 sv = *(const float4*)(x + (size_t)i * R + 4 * lane);  // self, fp32 exact
    a0 = sn * sv.x; a1 = sn * sv.y; a2 = sn * sv.z; a3 = sn * sv.w;
  }
  int jb = rp[i], je = rp[i + 1];
  for (int j = jb; j < je; j += 2) {
    int jc1 = min(j + 1, Ee - 1);
    int2 e0 = edge2[j];
    int2 e1 = edge2[jc1];
    float w0 = __int_as_float(e0.y);
    float w1 = (j + 1 < je) ? __int_as_float(e1.y) : 0.f;
    if (act) {
      uint2 g0 = *(const uint2*)(x16 + (size_t)e0.x * R + 4 * lane);
      uint2 g1 = *(const uint2*)(x16 + (size_t)e1.x * R + 4 * lane);
      float2 p01 = __half22float2(*reinterpret_cast<const __half2*>(&g0.x));
      float2 p23 = __half22float2(*reinterpret_cast<const __half2*>(&g0.y));
      float2 q01 = __half22float2(*reinterpret_cast<const __half2*>(&g1.x));
      float2 q23 = __half22float2(*reinterpret_cast<const __half2*>(&g1.y));
      a0 = fmaf(w0, p01.x, a0); a1 = fmaf(w0, p01.y, a1);
      a2 = fmaf(w0, p23.x, a2); a3 = fmaf(w0, p23.y, a3);
      a0 = fmaf(w1, q01.x, a0); a1 = fmaf(w1, q01.y, a1);
      a2 = fmaf(w1, q23.x, a2); a3 = fmaf(w1, q23.y, a3);
    }
  }
  if (act) {
#pragma unroll
    for (int k = 0; k < 4; k++) {
      int cch = 4 * lane + k;           // channel = f*T + t
      int f = cch / Tt, tt = cch % Tt;
      float val = (k == 0) ? a0 : (k == 1) ? a1 : (k == 2) ? a2 : a3;
      Px16[(size_t)tt * Nn * Ff + (size_t)i * Ff + f] = __float2half(val);
    }
  }
}

// ---------------- aggregation: wave per node, 16 lanes/edge x 8B, 4 edges/instr ----------------
__global__ __launch_bounds__(256) void k_agg64v(
    const __half* __restrict__ v, __half* __restrict__ outv,
    const int* __restrict__ rp, const int2* __restrict__ edge2,
    const float* __restrict__ dis) {
  int i = blockIdx.x * 4 + (threadIdx.x >> 6);
  if (i >= Nn) return;
  int lane = threadIdx.x & 63;
  int g = lane >> 4;   // edge slot 0..3
  int c = lane & 15;   // channel quad: 4c..4c+3
  float d = dis[i], sn = d * d;
  float a0, a1, a2, a3;
  {
    const uint2 gv = *(const uint2*)(v + (size_t)i * Hh + 4 * c);  // self
    float2 f01 = __half22float2(*reinterpret_cast<const __half2*>(&gv.x));
    float2 f23 = __half22float2(*reinterpret_cast<const __half2*>(&gv.y));
    float ws = (g == 0) ? sn : 0.f;
    a0 = ws * f01.x; a1 = ws * f01.y; a2 = ws * f23.x; a3 = ws * f23.y;
  }
  int jb = rp[i], je = rp[i + 1];
  for (int j0 = jb; j0 < je; j0 += 8) {
    int j1 = j0 + g;
    int j2 = j0 + 4 + g;
    int2 e1 = edge2[min(j1, Ee - 1)];
    int2 e2 = edge2[min(j2, Ee - 1)];
    float w1 = (j1 < je) ? __int_as_float(e1.y) : 0.f;
    float w2 = (j2 < je) ? __int_as_float(e2.y) : 0.f;
    const uint2 g1 = *(const uint2*)(v + (size_t)e1.x * Hh + 4 * c);
    const uint2 g2 = *(const uint2*)(v + (size_t)e2.x * Hh + 4 * c);
    float2 p01 = __half22float2(*reinterpret_cast<const __half2*>(&g1.x));
    float2 p23 = __half22float2(*reinterpret_cast<const __half2*>(&g1.y));
    float2 q01 = __half22float2(*reinterpret_cast<const __half2*>(&g2.x));
    float2 q23 = __half22float2(*reinterpret_cast<const __half2*>(&g2.y));
    a0 = fmaf(w1, p01.x, a0); a1 = fmaf(w1, p01.y, a1);
    a2 = fmaf(w1, p23.x, a2); a3 = fmaf(w1, p23.y, a3);
    a0 = fmaf(w2, q01.x, a0); a1 = fmaf(w2, q01.y, a1);
    a2 = fmaf(w2, q23.x, a2); a3 = fmaf(w2, q23.y, a3);
  }
  a0 += __shfl_xor(a0, 16, 64); a1 += __shfl_xor(a1, 16, 64);
  a2 += __shfl_xor(a2, 16, 64); a3 += __shfl_xor(a3, 16, 64);
  a0 += __shfl_xor(a0, 32, 64); a1 += __shfl_xor(a1, 32, 64);
  a2 += __shfl_xor(a2, 32, 64); a3 += __shfl_xor(a3, 32, 64);
  if (lane < 16) {
    __half2 h01, h23;
    h01.x = __float2half_rn(a0); h01.y = __float2half_rn(a1);
    h23.x = __float2half_rn(a2); h23.y = __float2half_rn(a3);
    uint2 st;
    st.x = *reinterpret_cast<unsigned int*>(&h01);
    st.y = *reinterpret_cast<unsigned int*>(&h23);
    *(uint2*)(outv + (size_t)i * Hh + 4 * c) = st;
  }
}

// shared helper: stage 16 nodes x 80 channels (fp16 sources) into fp32 LDS
static __device__ __forceinline__ void stage_x(
    float (*sX)[Cc], const __half* __restrict__ Px16t, const __half* __restrict__ P64,
    int i0, int tid) {
  if (tid < 160) {
    int n = tid / 10, r = tid % 10;
    int i = i0 + n;
    uint4 raw = make_uint4(0u, 0u, 0u, 0u);
    if (i < Nn) {
      raw = (r < 2) ? *(const uint4*)(Px16t + (size_t)i * Ff + r * 8)
                    : *(const uint4*)(P64 + (size_t)i * Hh + (r - 2) * 8);
    }
    float2 f0 = __half22float2(*reinterpret_cast<const __half2*>(&raw.x));
    float2 f1 = __half22float2(*reinterpret_cast<const __half2*>(&raw.y));
    float2 f2 = __half22float2(*reinterpret_cast<const __half2*>(&raw.z));
    float2 f3 = __half22float2(*reinterpret_cast<const __half2*>(&raw.w));
    float* dst = &sX[n][r * 8];
    dst[0] = f0.x; dst[1] = f0.y; dst[2] = f1.x; dst[3] = f1.y;
    dst[4] = f2.x; dst[5] = f2.y; dst[6] = f3.x; dst[7] = f3.y;
  }
}

// ---------------- GEMM z/r: (Wz,Wr) packed as __half2 -> 25 KB LDS, half the weight reads ----------------
// NOTE: no waves-per-EU hint — on this toolchain the 2nd __launch_bounds__ arg
// forces a VGPR cap the compiler satisfies by spilling to scratch (GB-scale
// WRITE_SIZE, 10-30x dur). Measured rounds 2/6.
__global__ __launch_bounds__(256) void k_gemm_zr(
    const __half* __restrict__ Px16, const __half* __restrict__ Ph16,
    const __half* __restrict__ h16,
    const float* __restrict__ Wz, const float* __restrict__ bz,
    const float* __restrict__ Wr, const float* __restrict__ br,
    __half* __restrict__ zb16, __half* __restrict__ rh16, int tstep) {
  __shared__ __half2 sWzr[Cc * Hh];  // 20 KB: {wz, wr} per (c,o)
  __shared__ float sX[16][Cc];       // 5 KB
  const int tid = threadIdx.x;
  const int i0 = blockIdx.x * 16;
  {
    const float4* wz4 = (const float4*)Wz;
    const float4* wr4 = (const float4*)Wr;
    for (int q = tid; q < (Cc * Hh) / 4; q += 256) {
      float4 z = wz4[q];
      float4 r = wr4[q];
      sWzr[4 * q + 0] = __floats2half2_rn(z.x, r.x);
      sWzr[4 * q + 1] = __floats2half2_rn(z.y, r.y);
      sWzr[4 * q + 2] = __floats2half2_rn(z.z, r.z);
      sWzr[4 * q + 3] = __floats2half2_rn(z.w, r.w);
    }
  }
  stage_x(sX, Px16 + (size_t)tstep * Nn * Ff, Ph16, i0, tid);
  __syncthreads();
  const int wv = tid >> 6, o = tid & 63;
  float az[4] = {0, 0, 0, 0}, ar[4] = {0, 0, 0, 0};
  for (int c = 0; c < Cc; c += 4) {
    float2 w0 = __half22float2(sWzr[(c + 0) * Hh + o]);
    float2 w1 = __half22float2(sWzr[(c + 1) * Hh + o]);
    float2 w2 = __half22float2(sWzr[(c + 2) * Hh + o]);
    float2 w3 = __half22float2(sWzr[(c + 3) * Hh + o]);
#pragma unroll
    for (int nd = 0; nd < 4; nd++) {
      const float4 xv = *(const float4*)&sX[wv * 4 + nd][c];
      az[nd] = fmaf(xv.x, w0.x, fmaf(xv.y, w1.x, fmaf(xv.z, w2.x, fmaf(xv.w, w3.x, az[nd]))));
      ar[nd] = fmaf(xv.x, w0.y, fmaf(xv.y, w1.y, fmaf(xv.z, w2.y, fmaf(xv.w, w3.y, ar[nd]))));
    }
  }
  float bzo = bz[o], bro = br[o];
#pragma unroll
  for (int nd = 0; nd < 4; nd++) {
    int i = i0 + wv * 4 + nd;
    if (i < Nn) {
      float zv = sigmoidf_(az[nd] + bzo);
      float rv = sigmoidf_(ar[nd] + bro);
      float hv = __half2float(h16[(size_t)i * Hh + o]);
      zb16[(size_t)i * Hh + o] = __float2half(zv);
      rh16[(size_t)i * Hh + o] = __float2half(rv * hv);
    }
  }
}

// ---------------- GEMM h: GRU update; writes h (fp32), h16, hs16[t] ----------------
__global__ __launch_bounds__(256) void k_gemm_h(
    const __half* __restrict__ Px16, const __half* __restrict__ Prh16,
    const __half* __restrict__ zb16, float* __restrict__ h, __half* __restrict__ h16,
    __half* __restrict__ hs16,
    const float* __restrict__ Wh, const float* __restrict__ bh, int tstep) {
  __shared__ float sWh[Cc * Hh];    // 20 KB
  __shared__ float sX[16][Cc];      // 5 KB
  const int tid = threadIdx.x;
  const int i0 = blockIdx.x * 16;
  {
    const float4* w4 = (const float4*)Wh;
    float4* s4 = (float4*)sWh;
    for (int q = tid; q < (Cc * Hh) / 4; q += 256) s4[q] = w4[q];
  }
  stage_x(sX, Px16 + (size_t)tstep * Nn * Ff, Prh16, i0, tid);
  __syncthreads();
  const int wv = tid >> 6, o = tid & 63;
  float ah[4] = {0, 0, 0, 0};
  for (int c = 0; c < Cc; c += 4) {
    float w0 = sWh[(c + 0) * Hh + o], w1 = sWh[(c + 1) * Hh + o];
    float w2 = sWh[(c + 2) * Hh + o], w3 = sWh[(c + 3) * Hh + o];
#pragma unroll
    for (int nd = 0; nd < 4; nd++) {
      const float4 xv = *(const float4*)&sX[wv * 4 + nd][c];
      ah[nd] = fmaf(xv.x, w0, fmaf(xv.y, w1, fmaf(xv.z, w2, fmaf(xv.w, w3, ah[nd]))));
    }
  }
  float bho = bh[o];
  __half* hst = hs16 + (size_t)tstep * Nn * Hh;
#pragma unroll
  for (int nd = 0; nd < 4; nd++) {
    int i = i0 + wv * 4 + nd;
    if (i < Nn) {
      float hc = tanhf(ah[nd] + bho);
      float zv = __half2float(zb16[(size_t)i * Hh + o]);
      float hv = h[(size_t)i * Hh + o];
      float hn = zv * hv + (1.0f - zv) * hc;
      h[(size_t)i * Hh + o] = hn;
      __half hh = __float2half(hn);
      h16[(size_t)i * Hh + o] = hh;
      hst[(size_t)i * Hh + o] = hh;
    }
  }
}

// ---------------- attention + output: wave per node over T=12 history ----------------
// Round-7 form (VGPR 44, 55% occupancy). Both loop-interchange variants regressed:
// r8 full (12 acc) spilled to 256 VGPR / 3.6 GB scratch; r9 TB=4 hit 144 VGPR / 11% occ.
__global__ __launch_bounds__(256) void k_att(
    const __half* __restrict__ hs16, const float* __restrict__ Wa,
    const float* __restrict__ ba, const float* __restrict__ cv,
    const float* __restrict__ Wfc, const float* __restrict__ bfc,
    float* __restrict__ out) {
  __shared__ float sWa[Hh * Hh];      // 16 KB
  __shared__ float sH[4][Tt][Hh];     // 12 KB
  const int tid = threadIdx.x;
  {
    const float4* a4 = (const float4*)Wa;
    float4* sa4 = (float4*)sWa;
    for (int q = tid; q < (Hh * Hh) / 4; q += 256) sa4[q] = a4[q];
  }
  const int wv = tid >> 6, o = tid & 63;
  const int i = blockIdx.x * 4 + wv;
  if (i < Nn) {
#pragma unroll
    for (int t = 0; t < Tt; t++)
      sH[wv][t][o] = __half2float(hs16[(size_t)t * Nn * Hh + (size_t)i * Hh + o]);
  }
  __syncthreads();
  if (i >= Nn) return;
  float bao = ba[o], cvo = cv[o];
  float al[Tt];
#pragma unroll
  for (int t = 0; t < Tt; t++) {
    float sc = 0.f;
    for (int c = 0; c < Hh; c += 4) {
      const float4 hv4 = *(const float4*)&sH[wv][t][c];
      sc = fmaf(hv4.x, sWa[(c + 0) * Hh + o],
           fmaf(hv4.y, sWa[(c + 1) * Hh + o],
           fmaf(hv4.z, sWa[(c + 2) * Hh + o],
           fmaf(hv4.w, sWa[(c + 3) * Hh + o], sc))));
    }
    float ap = tanhf(sc + bao) * cvo;
#pragma unroll
    for (int off = 32; off >= 1; off >>= 1) ap += __shfl_xor(ap, off, 64);
    al[t] = ap;  // all lanes hold align[i][t]
  }
  float m = al[0];
#pragma unroll
  for (int t = 1; t < Tt; t++) m = fmaxf(m, al[t]);
  float s = 0.f;
#pragma unroll
  for (int t = 0; t < Tt; t++) { al[t] = expf(al[t] - m); s += al[t]; }
  float inv = 1.0f / s;
  float cx = 0.f;
#pragma unroll
  for (int t = 0; t < Tt; t++) cx = fmaf(al[t], sH[wv][t][o], cx);
  float p = cx * inv * Wfc[o];
#pragma unroll
  for (int off = 32; off >= 1; off >>= 1) p += __shfl_xor(p, off, 64);
  if (o == 0) out[i] = p + bfc[0];
}

extern "C" void kernel_launch(void* const* d_in, const int* in_sizes, int n_in,
                              void* d_out, int out_size, void* d_ws, size_t ws_size,
                              hipStream_t stream) {
  const float* x   = (const float*)d_in[0];
  const int* ei    = (const int*)d_in[1];
  const float* ew  = (const float*)d_in[2];
  const float* Wz  = (const float*)d_in[3];
  const float* bz  = (const float*)d_in[4];
  const float* Wr  = (const float*)d_in[5];
  const float* br  = (const float*)d_in[6];
  const float* Wh  = (const float*)d_in[7];
  const float* bh  = (const float*)d_in[8];
  const float* Wa  = (const float*)d_in[9];
  const float* ba  = (const float*)d_in[10];
  const float* cv  = (const float*)d_in[11];
  const float* Wfc = (const float*)d_in[12];
  const float* bfc = (const float*)d_in[13];
  float* out = (float*)d_out;

  char* w = (char*)d_ws;
  auto alloc = [&](size_t bytes) {
    char* p = w;
    w += (bytes + 255) & ~(size_t)255;
    return p;
  };
  unsigned long long* dc = (unsigned long long*)alloc((size_t)Nn * 8);
  float* dis = (float*)alloc((size_t)Nn * 4);
  int* cnt   = (int*)alloc((size_t)Nn * 4);
  int* rp    = (int*)alloc((size_t)(Nn + 1) * 4);
  int* cur   = (int*)alloc((size_t)Nn * 4);
  int2* edge2 = (int2*)alloc((size_t)Ee * 8);
  __half* x16  = (__half*)alloc((size_t)Nn * Ff * Tt * 2);
  __half* Px16 = (__half*)alloc((size_t)Tt * Nn * Ff * 2);
  float* h     = (float*)alloc((size_t)Nn * Hh * 4);
  __half* h16  = (__half*)alloc((size_t)Nn * Hh * 2);
  __half* rh16 = (__half*)alloc((size_t)Nn * Hh * 2);
  __half* zb16 = (__half*)alloc((size_t)Nn * Hh * 2);
  __half* Ph16 = (__half*)alloc((size_t)Nn * Hh * 2);
  __half* Prh16 = (__half*)alloc((size_t)Nn * Hh * 2);
  __half* hs16 = (__half*)alloc((size_t)Tt * Nn * Hh * 2);  // 76.8 MB history

  hipMemsetAsync(dc, 0, (size_t)Nn * 8, stream);
  hipMemsetAsync(h, 0, (size_t)Nn * Hh * 4, stream);
  hipMemsetAsync(h16, 0, (size_t)Nn * Hh * 2, stream);  // fp16 zero == 0x0000

  k_deg<<<(Ee + 255) / 256, 256, 0, stream>>>(ei, ew, dc);
  k_dis<<<(Nn + 255) / 256, 256, 0, stream>>>(dc, dis, cnt);
  k_scan<<<1, 1024, 0, stream>>>(cnt, rp, cur);
  k_scatter<<<(Ee + 255) / 256, 256, 0, stream>>>(ei, ew, dis, cur, edge2);
  {
    const size_t total = (size_t)Nn * Ff * Tt;
    k_cvt_x<<<(int)((total + 255) / 256), 256, 0, stream>>>(x, x16);
  }
  k_agg_px<<<(Nn + 3) / 4, 256, 0, stream>>>(x, x16, Px16, rp, edge2, dis);

  const int gGemm = (Nn + 15) / 16;  // 256-thread blocks, 16 nodes each
  const int gNode = (Nn + 3) / 4;
  for (int t = 0; t < Tt; t++) {
    k_agg64v<<<gNode, 256, 0, stream>>>(h16, Ph16, rp, edge2, dis);
    k_gemm_zr<<<gGemm, 256, 0, stream>>>(Px16, Ph16, h16, Wz, bz, Wr, br, zb16, rh16, t);
    k_agg64v<<<gNode, 256, 0, stream>>>(rh16, Prh16, rp, edge2, dis);
    k_gemm_h<<<gGemm, 256, 0, stream>>>(Px16, Prh16, zb16, h, h16, hs16, Wh, bh, t);
  }
  k_att<<<gNode, 256, 0, stream>>>(hs16, Wa, ba, cv, Wfc, bfc, out);
}